// Round 7
// baseline (33.552 us; speedup 1.0000x reference)
//
#include <hip/hip_runtime.h>

#define CDIM 128
#define HDIM 128
#define TILE 256     // nodes per node-block (8 waves x 32)
#define LIM  40960   // nodes cached in edge LDS (x4 B = 163840 B = full 160 KiB)

typedef short bf16x8 __attribute__((ext_vector_type(8)));
typedef float f32x16 __attribute__((ext_vector_type(16)));

// fp32 -> bf16 bits, round-to-nearest-even
static __device__ __forceinline__ short f2bf(float f) {
    union { float f; unsigned u; } v; v.f = f;
    unsigned r = v.u + 0x7FFFu + ((v.u >> 16) & 1u);
    return (short)(r >> 16);
}
static __device__ __forceinline__ unsigned pack2(float a, float b) {
    return (unsigned)(unsigned short)f2bf(a) | ((unsigned)(unsigned short)f2bf(b) << 16);
}

// ---------------------------------------------------------------------------
// Prologue: fragment-linear bf16 weights for 32x32x16 MFMA. Coalesced READS
// (id walks W linearly), scattered writes (L2). Inverse-verified:
//   k = ks*16 + (l>>5)*8 + j, n = ct*32 + (l&31).
// ---------------------------------------------------------------------------
__global__ __launch_bounds__(256) void prep_kernel(
    const float* __restrict__ W1, const float* __restrict__ W2,
    short* __restrict__ wf1, short* __restrict__ wf2)
{
    int id = blockIdx.x * 256 + threadIdx.x;   // 0..32767
    const float* src = (id < 16384) ? W1 : W2;
    short* dst = (id < 16384) ? wf1 : wf2;
    int rem = id & 16383;                      // linear over W[k][n]
    int k = rem >> 7, n = rem & 127;
    int ks = k >> 4, j = k & 7;
    int l  = (n & 31) + 32 * ((k >> 3) & 1);
    int ct = n >> 5;
    dst[((ct * 8 + ks) * 64 + l) * 8 + j] = f2bf(src[rem]);
}

// ---------------------------------------------------------------------------
// Node pass (256 nodes/block, 8 waves) + cast-output slice.
//   b < NTILES: stage both W layers once (64 KB DMA) || x-loads to regs ->
//   barrier -> L1 MFMA -> pack h1 (P; partner Q via shfl 32) -> L2 MFMA with
//   in-register B frag -> per-lane dot + shfl(32) -> tab.
//   ALL blocks: grid-strided cast stream out[2E+i] = float(ein[i]).
// ---------------------------------------------------------------------------
__global__ __launch_bounds__(512) void node_mfma(
    const float* __restrict__ x,
    const short* __restrict__ wf1, const float* __restrict__ b1,
    const short* __restrict__ wf2, const float* __restrict__ b2,
    const float* __restrict__ We,
    const int* __restrict__ ein,
    unsigned* __restrict__ tab, float* __restrict__ out, int N, int E)
{
    __shared__ __align__(16) short wfA[2][16384];  // 64 KB: both layers
    __shared__ __align__(16) float cv[512];        // b1 | b2 | Wq | Wk

    const int tid = threadIdx.x;
    const int w   = tid >> 6;        // wave 0..7
    const int l   = tid & 63;
    const int col = l & 31;
    const int hi  = l >> 5;
    const int node = blockIdx.x * TILE + w * 32 + col;
    const bool nodeblk = (blockIdx.x * TILE) < N;

    if (nodeblk) {
        // ---- issue async weight staging (both layers, 4096 uint4) ----
#pragma unroll
        for (int t = 0; t < 8; t++) {
            int c = (t * 8 + w) * 64;   // wave-uniform uint4 chunk base
            const uint4* src = (c < 2048) ? ((const uint4*)wf1 + c)
                                          : ((const uint4*)wf2 + (c - 2048));
            __builtin_amdgcn_global_load_lds(
                (const __attribute__((address_space(1))) void*)(src + l),
                (__attribute__((address_space(3))) void*)((char*)wfA + (size_t)c * 16),
                16, 0, 0);
        }
        cv[tid] = (tid < 128) ? b1[tid] : (tid < 256) ? b2[tid - 128] : We[tid - 256];

        // ---- load + convert ALL x fragments to registers (overlaps DMA) ----
        const int nclamp = (node < N) ? node : (N - 1);
        const float* xb = &x[(size_t)nclamp * CDIM + hi * 8];
        bf16x8 af[8];
#pragma unroll
        for (int ks = 0; ks < 8; ks++) {
            float4 v0 = *(const float4*)(xb + ks * 16);
            float4 v1 = *(const float4*)(xb + ks * 16 + 4);
            af[ks][0] = f2bf(v0.x); af[ks][1] = f2bf(v0.y);
            af[ks][2] = f2bf(v0.z); af[ks][3] = f2bf(v0.w);
            af[ks][4] = f2bf(v1.x); af[ks][5] = f2bf(v1.y);
            af[ks][6] = f2bf(v1.z); af[ks][7] = f2bf(v1.w);
        }
        __syncthreads();   // weights + cv ready

        const f32x16 zz = {0.f,0.f,0.f,0.f,0.f,0.f,0.f,0.f,0.f,0.f,0.f,0.f,0.f,0.f,0.f,0.f};

        // ---- layer 1: A = W1-frag (LDS, lane-linear), B = x^T-frag (regs) ----
        f32x16 acc[4];
#pragma unroll
        for (int ct = 0; ct < 4; ct++) acc[ct] = zz;
#pragma unroll
        for (int ks = 0; ks < 8; ks++) {
#pragma unroll
            for (int ct = 0; ct < 4; ct++) {
                bf16x8 wfrag = *(const bf16x8*)&wfA[0][((ct * 8 + ks) * 64 + l) * 8];
                acc[ct] = __builtin_amdgcn_mfma_f32_32x32x16_bf16(wfrag, af[ks], acc[ct], 0, 0, 0);
            }
        }

        // ---- h1 = relu(D1 + b1): pack own 64 features as bf16 pairs ----
        unsigned P[4][4][2], Q[4][4][2];
#pragma unroll
        for (int ct = 0; ct < 4; ct++) {
#pragma unroll
            for (int g = 0; g < 4; g++) {
                float4 bv = *(const float4*)&cv[32 * ct + 8 * g + 4 * hi];
                float h0  = fmaxf(acc[ct][4 * g + 0] + bv.x, 0.f);
                float h1v = fmaxf(acc[ct][4 * g + 1] + bv.y, 0.f);
                float h2v = fmaxf(acc[ct][4 * g + 2] + bv.z, 0.f);
                float h3v = fmaxf(acc[ct][4 * g + 3] + bv.w, 0.f);
                P[ct][g][0] = pack2(h0, h1v);
                P[ct][g][1] = pack2(h2v, h3v);
            }
        }
#pragma unroll
        for (int ct = 0; ct < 4; ct++)
#pragma unroll
            for (int g = 0; g < 4; g++)
#pragma unroll
                for (int p = 0; p < 2; p++)
                    Q[ct][g][p] = (unsigned)__shfl_xor((int)P[ct][g][p], 32, 64);

        // ---- layer 2: B2 frag in-register; A = W2-frag from LDS ----
        f32x16 acc2[4];
#pragma unroll
        for (int ct = 0; ct < 4; ct++) acc2[ct] = zz;
#pragma unroll
        for (int ks2 = 0; ks2 < 8; ks2++) {
            const int c  = ks2 >> 1;
            const int s2 = (ks2 & 1) * 2;
            union { bf16x8 v; unsigned u[4]; } bb;
            bb.u[0] = hi ? Q[c][s2 + 1][0] : P[c][s2][0];
            bb.u[1] = hi ? Q[c][s2 + 1][1] : P[c][s2][1];
            bb.u[2] = hi ? P[c][s2 + 1][0] : Q[c][s2][0];
            bb.u[3] = hi ? P[c][s2 + 1][1] : Q[c][s2][1];
#pragma unroll
            for (int ct = 0; ct < 4; ct++) {
                bf16x8 wfrag = *(const bf16x8*)&wfA[1][((ct * 8 + ks2) * 64 + l) * 8];
                acc2[ct] = __builtin_amdgcn_mfma_f32_32x32x16_bf16(wfrag, bb.v, acc2[ct], 0, 0, 0);
            }
        }

        // ---- epilogue: partial dot over own 64 n2, combine across lane pair ----
        float pq = 0.f, pk = 0.f;
#pragma unroll
        for (int ct = 0; ct < 4; ct++) {
#pragma unroll
            for (int g = 0; g < 4; g++) {
                float4 b2v = *(const float4*)&cv[128 + 32 * ct + 8 * g + 4 * hi];
                float4 wqv = *(const float4*)&cv[256 + 32 * ct + 8 * g + 4 * hi];
                float4 wkv = *(const float4*)&cv[384 + 32 * ct + 8 * g + 4 * hi];
                const float* b2a = (const float*)&b2v;
                const float* wqa = (const float*)&wqv;
                const float* wka = (const float*)&wkv;
#pragma unroll
                for (int i = 0; i < 4; i++) {
                    float hv = fmaxf(acc2[ct][4 * g + i] + b2a[i], 0.f);
                    pq = fmaf(hv, wqa[i], pq);
                    pk = fmaf(hv, wka[i], pk);
                }
            }
        }
        pq += __shfl_xor(pq, 32, 64);
        pk += __shfl_xor(pk, 32, 64);
        if (hi == 0 && node < N) tab[node] = pack2(pq, pk);
    }

    // ---- cast slice (all blocks): out[2E + i] = float(ein[i]), i in [0,2E) ----
    {
        const int castU = (E * 2) >> 2;                    // int4 count (2E/4)
        const int chunk = (castU + gridDim.x - 1) / gridDim.x;
        const int base = blockIdx.x * chunk;
        const int lim = min(castU, base + chunk);
        const int4* ein4 = (const int4*)ein;
        float4* o4 = (float4*)out + (E >> 1);              // 2E floats = E/2 float4
        for (int i = base + tid; i < lim; i += 512) {
            int4 v = ein4[i];
            o4[i] = make_float4((float)v.x, (float)v.y, (float)v.z, (float)v.w);
        }
    }
}

// ---------------------------------------------------------------------------
// Edge pass (lean): phase A issues table-staging DMA + preloads ein(u0,u1) and
// eip(u0) [24 carried VGPRs]; phase B is gathers + score stores only.
// ---------------------------------------------------------------------------
__global__ __launch_bounds__(1024) void edge_kernel(
    const int* __restrict__ eip, const int* __restrict__ ein,
    const unsigned* __restrict__ tab, const float* __restrict__ be_p,
    float* __restrict__ out, int E)
{
    __shared__ __align__(16) unsigned lt[LIM];   // 163840 B
    const int tid = threadIdx.x;
    const int wv = tid >> 6, ln = tid & 63;

    // ---- issue async staging DMA: 10240 uint4, 16 waves x 10 iters ----
    const uint4* tg4 = (const uint4*)tab;
#pragma unroll
    for (int t = 0; t < LIM / 4 / 1024; t++) {
        int c = (t * 16 + wv) * 64;
        __builtin_amdgcn_global_load_lds(
            (const __attribute__((address_space(1))) void*)(tg4 + c + ln),
            (__attribute__((address_space(3))) void*)((char*)lt + (size_t)c * 16),
            16, 0, 0);
    }
    __builtin_amdgcn_sched_barrier(0);

    const int U = E >> 2;                         // 4-edge units (E % 4 == 0)
    const int chunk = (U + gridDim.x - 1) / gridDim.x;
    const int ustart = blockIdx.x * chunk;
    const int uend = min(U, ustart + chunk);

    const int4* eip4 = (const int4*)eip;
    const int4* ein4 = (const int4*)ein;
    float4* out4 = (float4*)out;

    const int u0 = ustart + tid, u1 = u0 + 1024;
    const bool v0 = u0 < uend, v1 = u1 < uend;

    int4 ns0 = {0,0,0,0}, nd0 = {0,0,0,0}, ns1 = {0,0,0,0}, nd1 = {0,0,0,0};
    int4 ps0 = {0,0,0,0}, pd0 = {0,0,0,0};
    if (v0) {
        ns0 = ein4[u0]; nd0 = ein4[U + u0];
        ps0 = eip4[u0]; pd0 = eip4[U + u0];
    }
    if (v1) { ns1 = ein4[u1]; nd1 = ein4[U + u1]; }

    __syncthreads();   // drains DMA + preloads; lt visible

    const float be = be_p[0];
#define GATHER(i) ((i) < LIM ? lt[i] : tab[i])
#define SCORE(us, ud) (__uint_as_float((us) << 16) + __uint_as_float((ud) & 0xFFFF0000u) + be)
    if (v0) {
        unsigned a0 = GATHER(ps0.x), a1 = GATHER(ps0.y), a2 = GATHER(ps0.z), a3 = GATHER(ps0.w);
        unsigned b0 = GATHER(pd0.x), b1 = GATHER(pd0.y), b2 = GATHER(pd0.z), b3 = GATHER(pd0.w);
        out4[u0] = make_float4(SCORE(a0,b0), SCORE(a1,b1), SCORE(a2,b2), SCORE(a3,b3));
        unsigned c0 = GATHER(ns0.x), c1 = GATHER(ns0.y), c2 = GATHER(ns0.z), c3 = GATHER(ns0.w);
        unsigned d0 = GATHER(nd0.x), d1 = GATHER(nd0.y), d2 = GATHER(nd0.z), d3 = GATHER(nd0.w);
        out4[U + u0] = make_float4(SCORE(c0,d0), SCORE(c1,d1), SCORE(c2,d2), SCORE(c3,d3));
    }
    if (v1) {
        int4 ps1 = eip4[u1], pd1 = eip4[U + u1];
        unsigned a0 = GATHER(ps1.x), a1 = GATHER(ps1.y), a2 = GATHER(ps1.z), a3 = GATHER(ps1.w);
        unsigned b0 = GATHER(pd1.x), b1 = GATHER(pd1.y), b2 = GATHER(pd1.z), b3 = GATHER(pd1.w);
        out4[u1] = make_float4(SCORE(a0,b0), SCORE(a1,b1), SCORE(a2,b2), SCORE(a3,b3));
        unsigned c0 = GATHER(ns1.x), c1 = GATHER(ns1.y), c2 = GATHER(ns1.z), c3 = GATHER(ns1.w);
        unsigned d0 = GATHER(nd1.x), d1 = GATHER(nd1.y), d2 = GATHER(nd1.z), d3 = GATHER(nd1.w);
        out4[U + u1] = make_float4(SCORE(c0,d0), SCORE(c1,d1), SCORE(c2,d2), SCORE(c3,d3));
    }
#undef GATHER
#undef SCORE
}

extern "C" void kernel_launch(void* const* d_in, const int* in_sizes, int n_in,
                              void* d_out, int out_size, void* d_ws, size_t ws_size,
                              hipStream_t stream) {
    const float* x   = (const float*)d_in[0];
    const int*   eip = (const int*)d_in[1];
    const int*   ein = (const int*)d_in[2];
    // d_in[3] = batch (unused)
    const float* W1  = (const float*)d_in[4];
    const float* b1  = (const float*)d_in[5];
    const float* W2  = (const float*)d_in[6];
    const float* b2  = (const float*)d_in[7];
    const float* We  = (const float*)d_in[8];
    const float* be  = (const float*)d_in[9];

    const int N = in_sizes[0] / CDIM;
    const int E = in_sizes[1] / 2;

    // workspace: [0, 200704) packed bf16x2 score table; then fragment-linear W
    char* ws = (char*)d_ws;
    unsigned* tab = (unsigned*)ws;                   // N*4 B
    short*    wf1 = (short*)(ws + 200704);           // 32768 B
    short*    wf2 = (short*)(ws + 200704 + 32768);   // 32768 B

    prep_kernel<<<128, 256, 0, stream>>>(W1, W2, wf1, wf2);
    node_mfma<<<256, 512, 0, stream>>>(x, wf1, b1, wf2, b2, We, ein, tab,
                                       (float*)d_out, N, E);
    edge_kernel<<<256, 1024, 0, stream>>>(eip, ein, tab, be, (float*)d_out, E);
}

// Round 8
// 29.696 us; speedup vs baseline: 1.1298x; 1.1298x over previous
//
#include <hip/hip_runtime.h>

#define CDIM 128
#define HDIM 128
#define LIM  40960   // nodes cached in edge LDS (x4 B = 163840 B = full 160 KiB)

typedef short bf16x8 __attribute__((ext_vector_type(8)));
typedef float f32x16 __attribute__((ext_vector_type(16)));

// fp32 -> bf16 bits, round-to-nearest-even
static __device__ __forceinline__ short f2bf(float f) {
    union { float f; unsigned u; } v; v.f = f;
    unsigned r = v.u + 0x7FFFu + ((v.u >> 16) & 1u);
    return (short)(r >> 16);
}
static __device__ __forceinline__ unsigned pack2(float a, float b) {
    return (unsigned)(unsigned short)f2bf(a) | ((unsigned)(unsigned short)f2bf(b) << 16);
}

// ---------------------------------------------------------------------------
// Node pass (R5 structure + in-block W transform; no prep kernel).
// 256 thr (4 waves), 128 nodes/block, 2 blocks/CU.
//   issue x loads to regs -> transform W1,W2 fp32->fragment-linear bf16 LDS
//   (1 ds_write_b128/thread/iter, coalesced W reads) -> barrier ->
//   L1 MFMA -> pack h1 (P; partner Q via shfl 32) -> L2 MFMA (in-reg B frag)
//   -> per-lane dot + shfl(32) -> tab.
// Fragment map (32x32x16): operand idx = lane&31, k = ks*16 + 8*(lane>>5)+j;
// D: col = lane&31, row = (r&3) + 8*(r>>2) + 4*(lane>>5).
// ---------------------------------------------------------------------------
__global__ __launch_bounds__(256, 2) void node_mfma(
    const float* __restrict__ x,
    const float* __restrict__ W1, const float* __restrict__ b1,
    const float* __restrict__ W2, const float* __restrict__ b2,
    const float* __restrict__ We,
    unsigned* __restrict__ tab, int N)
{
    __shared__ __align__(16) short wfA[2][16384];  // 64 KB: both layers
    __shared__ __align__(16) float cv[512];        // b1 | b2 | Wq | Wk

    const int tid = threadIdx.x;
    const int l   = tid & 63;
    const int col = l & 31;
    const int hi  = l >> 5;
    const int node = blockIdx.x * 128 + (tid >> 6) * 32 + col;

    // ---- issue ALL x loads first (latency hides under W transform) ----
    const int nclamp = (node < N) ? node : (N - 1);
    const float* xb = &x[(size_t)nclamp * CDIM + hi * 8];
    float4 xr[16];
#pragma unroll
    for (int ks = 0; ks < 8; ks++) {
        xr[2 * ks]     = *(const float4*)(xb + ks * 16);
        xr[2 * ks + 1] = *(const float4*)(xb + ks * 16 + 4);
    }

    // ---- W transform: both layers, dest-linear, 1 ds_write_b128/iter ----
    // tt = (layer<<11) | (ct<<9) | (ks<<6) | lv ; dest short off = (tt&2047)*8
#pragma unroll
    for (int t = 0; t < 16; t++) {
        int tt = t * 256 + tid;
        int layer = tt >> 11;
        int rem = tt & 2047;
        int lv = rem & 63, ks = (rem >> 6) & 7, ct = rem >> 9;
        const float* Wsrc = layer ? W2 : W1;
        int k0 = ks * 16 + 8 * (lv >> 5);
        int n  = ct * 32 + (lv & 31);
        bf16x8 wv;
#pragma unroll
        for (int j = 0; j < 8; j++) wv[j] = f2bf(Wsrc[(k0 + j) * HDIM + n]);
        *(bf16x8*)&wfA[layer][rem * 8] = wv;
    }
    for (int i = tid; i < 512; i += 256)
        cv[i] = (i < 128) ? b1[i] : (i < 256) ? b2[i - 128] : We[i - 256];

    // ---- convert x to bf16 fragments ----
    bf16x8 af[8];
#pragma unroll
    for (int ks = 0; ks < 8; ks++) {
        float4 v0 = xr[2 * ks], v1 = xr[2 * ks + 1];
        af[ks][0] = f2bf(v0.x); af[ks][1] = f2bf(v0.y);
        af[ks][2] = f2bf(v0.z); af[ks][3] = f2bf(v0.w);
        af[ks][4] = f2bf(v1.x); af[ks][5] = f2bf(v1.y);
        af[ks][6] = f2bf(v1.z); af[ks][7] = f2bf(v1.w);
    }
    __syncthreads();   // wfA + cv ready

    const f32x16 zz = {0.f,0.f,0.f,0.f,0.f,0.f,0.f,0.f,0.f,0.f,0.f,0.f,0.f,0.f,0.f,0.f};

    // ---- layer 1: A = W1-frag (LDS, lane-linear), B = x^T-frag (regs) ----
    f32x16 acc[4];
#pragma unroll
    for (int ct = 0; ct < 4; ct++) acc[ct] = zz;
#pragma unroll
    for (int ks = 0; ks < 8; ks++) {
#pragma unroll
        for (int ct = 0; ct < 4; ct++) {
            bf16x8 wfrag = *(const bf16x8*)&wfA[0][((ct * 8 + ks) * 64 + l) * 8];
            acc[ct] = __builtin_amdgcn_mfma_f32_32x32x16_bf16(wfrag, af[ks], acc[ct], 0, 0, 0);
        }
    }

    // ---- h1 = relu(D1 + b1): pack own 64 features as bf16 pairs ----
    unsigned P[4][4][2], Q[4][4][2];
#pragma unroll
    for (int ct = 0; ct < 4; ct++) {
#pragma unroll
        for (int g = 0; g < 4; g++) {
            float4 bv = *(const float4*)&cv[32 * ct + 8 * g + 4 * hi];
            float h0  = fmaxf(acc[ct][4 * g + 0] + bv.x, 0.f);
            float h1v = fmaxf(acc[ct][4 * g + 1] + bv.y, 0.f);
            float h2v = fmaxf(acc[ct][4 * g + 2] + bv.z, 0.f);
            float h3v = fmaxf(acc[ct][4 * g + 3] + bv.w, 0.f);
            P[ct][g][0] = pack2(h0, h1v);
            P[ct][g][1] = pack2(h2v, h3v);
        }
    }
#pragma unroll
    for (int ct = 0; ct < 4; ct++)
#pragma unroll
        for (int g = 0; g < 4; g++)
#pragma unroll
            for (int p = 0; p < 2; p++)
                Q[ct][g][p] = (unsigned)__shfl_xor((int)P[ct][g][p], 32, 64);

    // ---- layer 2: B2 frag in-register; A = W2-frag from LDS ----
    f32x16 acc2[4];
#pragma unroll
    for (int ct = 0; ct < 4; ct++) acc2[ct] = zz;
#pragma unroll
    for (int ks2 = 0; ks2 < 8; ks2++) {
        const int c  = ks2 >> 1;
        const int s2 = (ks2 & 1) * 2;
        union { bf16x8 v; unsigned u[4]; } bb;
        bb.u[0] = hi ? Q[c][s2 + 1][0] : P[c][s2][0];
        bb.u[1] = hi ? Q[c][s2 + 1][1] : P[c][s2][1];
        bb.u[2] = hi ? P[c][s2 + 1][0] : Q[c][s2][0];
        bb.u[3] = hi ? P[c][s2 + 1][1] : Q[c][s2][1];
#pragma unroll
        for (int ct = 0; ct < 4; ct++) {
            bf16x8 wfrag = *(const bf16x8*)&wfA[1][((ct * 8 + ks2) * 64 + l) * 8];
            acc2[ct] = __builtin_amdgcn_mfma_f32_32x32x16_bf16(wfrag, bb.v, acc2[ct], 0, 0, 0);
        }
    }

    // ---- epilogue: partial dot over own 64 n2, combine across lane pair ----
    float pq = 0.f, pk = 0.f;
#pragma unroll
    for (int ct = 0; ct < 4; ct++) {
#pragma unroll
        for (int g = 0; g < 4; g++) {
            float4 b2v = *(const float4*)&cv[128 + 32 * ct + 8 * g + 4 * hi];
            float4 wqv = *(const float4*)&cv[256 + 32 * ct + 8 * g + 4 * hi];
            float4 wkv = *(const float4*)&cv[384 + 32 * ct + 8 * g + 4 * hi];
            const float* b2a = (const float*)&b2v;
            const float* wqa = (const float*)&wqv;
            const float* wka = (const float*)&wkv;
#pragma unroll
            for (int i = 0; i < 4; i++) {
                float hv = fmaxf(acc2[ct][4 * g + i] + b2a[i], 0.f);
                pq = fmaf(hv, wqa[i], pq);
                pk = fmaf(hv, wka[i], pk);
            }
        }
    }
    pq += __shfl_xor(pq, 32, 64);
    pk += __shfl_xor(pk, 32, 64);
    if (hi == 0 && node < N) tab[node] = pack2(pq, pk);
}

// ---------------------------------------------------------------------------
// Edge pass (R5 form, best measured): phase A = staging DMA + cast outputs +
// carry ein indices; phase B = gathers + score stores.
// ---------------------------------------------------------------------------
__global__ __launch_bounds__(1024) void edge_kernel(
    const int* __restrict__ eip, const int* __restrict__ ein,
    const unsigned* __restrict__ tab, const float* __restrict__ be_p,
    float* __restrict__ out, int E)
{
    __shared__ __align__(16) unsigned lt[LIM];   // 163840 B
    const int tid = threadIdx.x;
    const int wv = tid >> 6, ln = tid & 63;

    // ---- issue async staging DMA: 10240 uint4, 16 waves x 10 iters ----
    const uint4* tg4 = (const uint4*)tab;
#pragma unroll
    for (int t = 0; t < LIM / 4 / 1024; t++) {
        int c = (t * 16 + wv) * 64;
        __builtin_amdgcn_global_load_lds(
            (const __attribute__((address_space(1))) void*)(tg4 + c + ln),
            (__attribute__((address_space(3))) void*)((char*)lt + (size_t)c * 16),
            16, 0, 0);
    }
    __builtin_amdgcn_sched_barrier(0);

    const int U = E >> 2;                         // 4-edge units (E % 4 == 0)
    const int chunk = (U + gridDim.x - 1) / gridDim.x;
    const int ustart = blockIdx.x * chunk;
    const int uend = min(U, ustart + chunk);

    const int4* eip4 = (const int4*)eip;
    const int4* ein4 = (const int4*)ein;
    float4* out4 = (float4*)out;

    // ---- phase A: cast outputs (overlaps DMA); keep ein indices in regs ----
    const int u0 = ustart + tid, u1 = u0 + 1024;
    const bool v0 = u0 < uend, v1 = u1 < uend;
    int4 ns0 = {0,0,0,0}, nd0 = {0,0,0,0}, ns1 = {0,0,0,0}, nd1 = {0,0,0,0};
    if (v0) {
        ns0 = ein4[u0]; nd0 = ein4[U + u0];
        out4[2 * U + u0] = make_float4((float)ns0.x, (float)ns0.y, (float)ns0.z, (float)ns0.w);
        out4[3 * U + u0] = make_float4((float)nd0.x, (float)nd0.y, (float)nd0.z, (float)nd0.w);
    }
    if (v1) {
        ns1 = ein4[u1]; nd1 = ein4[U + u1];
        out4[2 * U + u1] = make_float4((float)ns1.x, (float)ns1.y, (float)ns1.z, (float)ns1.w);
        out4[3 * U + u1] = make_float4((float)nd1.x, (float)nd1.y, (float)nd1.z, (float)nd1.w);
    }
    __syncthreads();   // drains DMA (vmcnt) + makes lt visible

    const float be = be_p[0];
#define GATHER(i) ((i) < LIM ? lt[i] : tab[i])
#define SCORE(us, ud) (__uint_as_float((us) << 16) + __uint_as_float((ud) & 0xFFFF0000u) + be)

    // ---- phase B: score outputs ----
    if (v0) {
        int4 ps = eip4[u0], pd = eip4[U + u0];
        unsigned a0 = GATHER(ps.x), a1 = GATHER(ps.y), a2 = GATHER(ps.z), a3 = GATHER(ps.w);
        unsigned b0 = GATHER(pd.x), b1 = GATHER(pd.y), b2 = GATHER(pd.z), b3 = GATHER(pd.w);
        unsigned c0 = GATHER(ns0.x), c1 = GATHER(ns0.y), c2 = GATHER(ns0.z), c3 = GATHER(ns0.w);
        unsigned d0 = GATHER(nd0.x), d1 = GATHER(nd0.y), d2 = GATHER(nd0.z), d3 = GATHER(nd0.w);
        out4[u0]     = make_float4(SCORE(a0,b0), SCORE(a1,b1), SCORE(a2,b2), SCORE(a3,b3));
        out4[U + u0] = make_float4(SCORE(c0,d0), SCORE(c1,d1), SCORE(c2,d2), SCORE(c3,d3));
    }
    if (v1) {
        int4 ps = eip4[u1], pd = eip4[U + u1];
        unsigned a0 = GATHER(ps.x), a1 = GATHER(ps.y), a2 = GATHER(ps.z), a3 = GATHER(ps.w);
        unsigned b0 = GATHER(pd.x), b1 = GATHER(pd.y), b2 = GATHER(pd.z), b3 = GATHER(pd.w);
        unsigned c0 = GATHER(ns1.x), c1 = GATHER(ns1.y), c2 = GATHER(ns1.z), c3 = GATHER(ns1.w);
        unsigned d0 = GATHER(nd1.x), d1 = GATHER(nd1.y), d2 = GATHER(nd1.z), d3 = GATHER(nd1.w);
        out4[u1]     = make_float4(SCORE(a0,b0), SCORE(a1,b1), SCORE(a2,b2), SCORE(a3,b3));
        out4[U + u1] = make_float4(SCORE(c0,d0), SCORE(c1,d1), SCORE(c2,d2), SCORE(c3,d3));
    }
#undef GATHER
#undef SCORE
}

extern "C" void kernel_launch(void* const* d_in, const int* in_sizes, int n_in,
                              void* d_out, int out_size, void* d_ws, size_t ws_size,
                              hipStream_t stream) {
    const float* x   = (const float*)d_in[0];
    const int*   eip = (const int*)d_in[1];
    const int*   ein = (const int*)d_in[2];
    // d_in[3] = batch (unused)
    const float* W1  = (const float*)d_in[4];
    const float* b1  = (const float*)d_in[5];
    const float* W2  = (const float*)d_in[6];
    const float* b2  = (const float*)d_in[7];
    const float* We  = (const float*)d_in[8];
    const float* be  = (const float*)d_in[9];

    const int N = in_sizes[0] / CDIM;
    const int E = in_sizes[1] / 2;

    unsigned* tab = (unsigned*)d_ws;   // N*4 B packed bf16x2 score table

    node_mfma<<<(N + 127) / 128, 256, 0, stream>>>(x, W1, b1, W2, b2, We, tab, N);
    edge_kernel<<<256, 1024, 0, stream>>>(eip, ein, tab, be, (float*)d_out, E);
}